// Round 1
// baseline (5106.424 us; speedup 1.0000x reference)
//
#include <hip/hip_runtime.h>

#define V_N   100000
#define E_N   300000
#define IN_C  256
#define OUT_C 256
#define NREL2 474
#define BN_EPS 1e-5f

#define BM 64
#define KT 32
#define LDA (BM + 4)   // pad to 68 floats: float4 reads stay 16B-aligned, conflicts <=2-way

// ---------------- small kernels ----------------

__global__ void deg_kernel(const int* __restrict__ dst, float* __restrict__ deg) {
    int e = blockIdx.x * 256 + threadIdx.x;
    if (e < E_N) atomicAdd(&deg[dst[e]], 1.0f);
}

__global__ void invsqrt_kernel(float* deg) {
    int v = blockIdx.x * 256 + threadIdx.x;
    if (v < V_N) {
        float d = deg[v];
        deg[v] = d > 0.f ? rsqrtf(d) : 0.f;
    }
}

// ---------------- edge message GEMM (masked two-pass over dir) ----------------
// block: 64 edges x 256 cols, K-tiled by 32. blockIdx.y = dir.
__global__ __launch_bounds__(256)
void edge_gemm(const float* __restrict__ x, const float* __restrict__ rel_repr,
               const float* __restrict__ loop_rel, const float* __restrict__ w,
               const int* __restrict__ src, const int* __restrict__ dst,
               const int* __restrict__ etype, const int* __restrict__ edir,
               const float* __restrict__ inv, float* __restrict__ out)
{
    __shared__ float A_t[KT][LDA];      // A transposed: A_t[k][edge]
    __shared__ float w_lds[KT][OUT_C];  // w tile

    const int t  = threadIdx.x;
    const int d  = blockIdx.y;
    const int e0 = blockIdx.x * BM;

    // load-phase mapping: thread owns edge le, k-chunk kq*8..kq*8+7
    const int le = t & 63;
    const int kq = t >> 6;
    const int eg = e0 + le;

    int s_idx = 0, et = 0;
    bool active = false;
    if (eg < E_N) {
        active = (edir[eg] == d);
        s_idx  = src[eg];
        et     = etype[eg];
    }
    const float* xrow = x + (size_t)s_idx * IN_C;
    const float* rrow = (et < NREL2) ? (rel_repr + (size_t)et * IN_C) : loop_rel;
    const float* wmat = w + (size_t)d * IN_C * OUT_C;

    // compute-phase mapping: thread owns 4 edges (ec*4..+3) x 16 cols (cc*16..+15)
    const int ec = t & 15;
    const int cc = t >> 4;

    float4 acc[4][4];
    #pragma unroll
    for (int i = 0; i < 4; i++)
        #pragma unroll
        for (int j = 0; j < 4; j++) acc[i][j] = make_float4(0.f, 0.f, 0.f, 0.f);

    for (int k0 = 0; k0 < IN_C; k0 += KT) {
        const int kb = kq * 8;
        if (active) {
            float4 xv0 = *(const float4*)(xrow + k0 + kb);
            float4 xv1 = *(const float4*)(xrow + k0 + kb + 4);
            float4 rv0 = *(const float4*)(rrow + k0 + kb);
            float4 rv1 = *(const float4*)(rrow + k0 + kb + 4);
            A_t[kb + 0][le] = xv0.x * rv0.x;
            A_t[kb + 1][le] = xv0.y * rv0.y;
            A_t[kb + 2][le] = xv0.z * rv0.z;
            A_t[kb + 3][le] = xv0.w * rv0.w;
            A_t[kb + 4][le] = xv1.x * rv1.x;
            A_t[kb + 5][le] = xv1.y * rv1.y;
            A_t[kb + 6][le] = xv1.z * rv1.z;
            A_t[kb + 7][le] = xv1.w * rv1.w;
        } else {
            #pragma unroll
            for (int i = 0; i < 8; i++) A_t[kb + i][le] = 0.f;
        }
        // w tile: 32 rows x 256 cols = 2048 float4; 8 per thread, coalesced
        #pragma unroll
        for (int i = 0; i < 8; i++) {
            int idx = i * 256 + t;
            int row = idx >> 6;
            int c4  = (idx & 63) << 2;
            *(float4*)&w_lds[row][c4] = *(const float4*)(wmat + (size_t)(k0 + row) * OUT_C + c4);
        }
        __syncthreads();

        #pragma unroll
        for (int k = 0; k < KT; k++) {
            float4 a = *(const float4*)&A_t[k][ec << 2];
            float4 wv0 = *(const float4*)&w_lds[k][cc * 16 + 0];
            float4 wv1 = *(const float4*)&w_lds[k][cc * 16 + 4];
            float4 wv2 = *(const float4*)&w_lds[k][cc * 16 + 8];
            float4 wv3 = *(const float4*)&w_lds[k][cc * 16 + 12];
            float av[4] = {a.x, a.y, a.z, a.w};
            #pragma unroll
            for (int i = 0; i < 4; i++) {
                acc[i][0].x += av[i] * wv0.x; acc[i][0].y += av[i] * wv0.y;
                acc[i][0].z += av[i] * wv0.z; acc[i][0].w += av[i] * wv0.w;
                acc[i][1].x += av[i] * wv1.x; acc[i][1].y += av[i] * wv1.y;
                acc[i][1].z += av[i] * wv1.z; acc[i][1].w += av[i] * wv1.w;
                acc[i][2].x += av[i] * wv2.x; acc[i][2].y += av[i] * wv2.y;
                acc[i][2].z += av[i] * wv2.z; acc[i][2].w += av[i] * wv2.w;
                acc[i][3].x += av[i] * wv3.x; acc[i][3].y += av[i] * wv3.y;
                acc[i][3].z += av[i] * wv3.z; acc[i][3].w += av[i] * wv3.w;
            }
        }
        __syncthreads();
    }

    // epilogue: scale by edge norm, scatter-add to out[dst]
    #pragma unroll
    for (int i = 0; i < 4; i++) {
        int ee = e0 + ec * 4 + i;
        if (ee >= E_N) continue;
        if (edir[ee] != d) continue;   // masked row: acc is zero anyway, skip atomics
        float en = inv[src[ee]] * inv[dst[ee]];
        float* base = out + (size_t)dst[ee] * OUT_C + cc * 16;
        #pragma unroll
        for (int j = 0; j < 4; j++) {
            atomicAdd(base + j * 4 + 0, acc[i][j].x * en);
            atomicAdd(base + j * 4 + 1, acc[i][j].y * en);
            atomicAdd(base + j * 4 + 2, acc[i][j].z * en);
            atomicAdd(base + j * 4 + 3, acc[i][j].w * en);
        }
    }
}

// ---------------- self-loop GEMM + combine ----------------
// out[v] = (agg[v] + (x[v]*loop_rel) @ w2) / 3 + bias
__global__ __launch_bounds__(256)
void self_gemm(const float* __restrict__ x, const float* __restrict__ loop_rel,
               const float* __restrict__ w2, const float* __restrict__ bias,
               float* __restrict__ out)
{
    __shared__ float A_t[KT][LDA];
    __shared__ float w_lds[KT][OUT_C];

    const int t  = threadIdx.x;
    const int v0 = blockIdx.x * BM;

    const int lv = t & 63;
    const int kq = t >> 6;
    const int vg = v0 + lv;
    const float* xrow = x + (size_t)(vg < V_N ? vg : 0) * IN_C;
    const bool vok = (vg < V_N);

    const int ec = t & 15;
    const int cc = t >> 4;

    float4 acc[4][4];
    #pragma unroll
    for (int i = 0; i < 4; i++)
        #pragma unroll
        for (int j = 0; j < 4; j++) acc[i][j] = make_float4(0.f, 0.f, 0.f, 0.f);

    for (int k0 = 0; k0 < IN_C; k0 += KT) {
        const int kb = kq * 8;
        if (vok) {
            float4 xv0 = *(const float4*)(xrow + k0 + kb);
            float4 xv1 = *(const float4*)(xrow + k0 + kb + 4);
            float4 rv0 = *(const float4*)(loop_rel + k0 + kb);
            float4 rv1 = *(const float4*)(loop_rel + k0 + kb + 4);
            A_t[kb + 0][lv] = xv0.x * rv0.x;
            A_t[kb + 1][lv] = xv0.y * rv0.y;
            A_t[kb + 2][lv] = xv0.z * rv0.z;
            A_t[kb + 3][lv] = xv0.w * rv0.w;
            A_t[kb + 4][lv] = xv1.x * rv1.x;
            A_t[kb + 5][lv] = xv1.y * rv1.y;
            A_t[kb + 6][lv] = xv1.z * rv1.z;
            A_t[kb + 7][lv] = xv1.w * rv1.w;
        } else {
            #pragma unroll
            for (int i = 0; i < 8; i++) A_t[kb + i][lv] = 0.f;
        }
        #pragma unroll
        for (int i = 0; i < 8; i++) {
            int idx = i * 256 + t;
            int row = idx >> 6;
            int c4  = (idx & 63) << 2;
            *(float4*)&w_lds[row][c4] = *(const float4*)(w2 + (size_t)(k0 + row) * OUT_C + c4);
        }
        __syncthreads();

        #pragma unroll
        for (int k = 0; k < KT; k++) {
            float4 a = *(const float4*)&A_t[k][ec << 2];
            float4 wv0 = *(const float4*)&w_lds[k][cc * 16 + 0];
            float4 wv1 = *(const float4*)&w_lds[k][cc * 16 + 4];
            float4 wv2 = *(const float4*)&w_lds[k][cc * 16 + 8];
            float4 wv3 = *(const float4*)&w_lds[k][cc * 16 + 12];
            float av[4] = {a.x, a.y, a.z, a.w};
            #pragma unroll
            for (int i = 0; i < 4; i++) {
                acc[i][0].x += av[i] * wv0.x; acc[i][0].y += av[i] * wv0.y;
                acc[i][0].z += av[i] * wv0.z; acc[i][0].w += av[i] * wv0.w;
                acc[i][1].x += av[i] * wv1.x; acc[i][1].y += av[i] * wv1.y;
                acc[i][1].z += av[i] * wv1.z; acc[i][1].w += av[i] * wv1.w;
                acc[i][2].x += av[i] * wv2.x; acc[i][2].y += av[i] * wv2.y;
                acc[i][2].z += av[i] * wv2.z; acc[i][2].w += av[i] * wv2.w;
                acc[i][3].x += av[i] * wv3.x; acc[i][3].y += av[i] * wv3.y;
                acc[i][3].z += av[i] * wv3.z; acc[i][3].w += av[i] * wv3.w;
            }
        }
        __syncthreads();
    }

    const float inv3 = 1.0f / 3.0f;
    #pragma unroll
    for (int i = 0; i < 4; i++) {
        int vv = v0 + ec * 4 + i;
        if (vv >= V_N) continue;
        float* base = out + (size_t)vv * OUT_C + cc * 16;
        #pragma unroll
        for (int j = 0; j < 4; j++) {
            float4 cur = *(const float4*)(base + j * 4);
            float4 b4  = *(const float4*)(bias + cc * 16 + j * 4);
            float4 r;
            r.x = (cur.x + acc[i][j].x) * inv3 + b4.x;
            r.y = (cur.y + acc[i][j].y) * inv3 + b4.y;
            r.z = (cur.z + acc[i][j].z) * inv3 + b4.z;
            r.w = (cur.w + acc[i][j].w) * inv3 + b4.w;
            *(float4*)(base + j * 4) = r;
        }
    }
}

// ---------------- BatchNorm ----------------

__global__ void bn_stats(const float* __restrict__ out, float* __restrict__ sums) {
    int t  = threadIdx.x;           // column
    int r0 = blockIdx.x * 256;
    float s = 0.f, s2 = 0.f;
    for (int i = 0; i < 256; i++) {
        int r = r0 + i;
        if (r < V_N) {
            float v = out[(size_t)r * OUT_C + t];
            s += v; s2 += v * v;
        }
    }
    atomicAdd(&sums[t], s);
    atomicAdd(&sums[256 + t], s2);
}

__global__ void bn_finalize(const float* __restrict__ sums, float* __restrict__ ms) {
    int t = threadIdx.x;
    float m   = sums[t] / (float)V_N;
    float var = sums[256 + t] / (float)V_N - m * m;
    ms[t]       = m;
    ms[256 + t] = rsqrtf(var + BN_EPS);
}

__global__ void bn_norm(float* __restrict__ out, const float* __restrict__ ms) {
    const size_t total4 = (size_t)V_N * OUT_C / 4;
    size_t stride = (size_t)gridDim.x * blockDim.x;
    for (size_t idx = (size_t)blockIdx.x * blockDim.x + threadIdx.x; idx < total4; idx += stride) {
        int c4 = (int)(idx & 63) << 2;
        float4 h = ((float4*)out)[idx];
        h.x = (h.x - ms[c4 + 0]) * ms[256 + c4 + 0];
        h.y = (h.y - ms[c4 + 1]) * ms[256 + c4 + 1];
        h.z = (h.z - ms[c4 + 2]) * ms[256 + c4 + 2];
        h.w = (h.w - ms[c4 + 3]) * ms[256 + c4 + 3];
        ((float4*)out)[idx] = h;
    }
}

// ---------------- rel_out: (rel_all @ w_rel)[:, 255] ----------------

__global__ void rel_out_kernel(const float* __restrict__ rel_repr,
                               const float* __restrict__ loop_rel,
                               const float* __restrict__ w_rel,
                               float* __restrict__ out)
{
    int r = blockIdx.x;
    const float* row = (r < NREL2) ? (rel_repr + (size_t)r * IN_C) : loop_rel;
    int l = threadIdx.x;   // 64 lanes
    float s = 0.f;
    #pragma unroll
    for (int q = 0; q < 4; q++) {
        int k = l + q * 64;
        s += row[k] * w_rel[(size_t)k * OUT_C + (OUT_C - 1)];
    }
    #pragma unroll
    for (int m = 32; m >= 1; m >>= 1) s += __shfl_xor(s, m);
    if (l == 0) out[(size_t)V_N * OUT_C + r] = s;
}

// ---------------- launch ----------------

extern "C" void kernel_launch(void* const* d_in, const int* in_sizes, int n_in,
                              void* d_out, int out_size, void* d_ws, size_t ws_size,
                              hipStream_t stream) {
    const float* x        = (const float*)d_in[0];
    const float* rel_repr = (const float*)d_in[1];
    const float* w        = (const float*)d_in[2];
    const float* w_rel    = (const float*)d_in[3];
    const float* loop_rel = (const float*)d_in[4];
    const float* bias     = (const float*)d_in[5];
    const int*   src      = (const int*)d_in[6];
    const int*   dst      = (const int*)d_in[7];
    const int*   etype    = (const int*)d_in[8];
    const int*   edir     = (const int*)d_in[9];
    float* out = (float*)d_out;

    float* degi = (float*)d_ws;        // V floats: deg -> inv_sqrt (in place)
    float* sums = degi + V_N;          // 512 floats: col sum, col sumsq
    float* ms   = sums + 512;          // 512 floats: mean, rsqrt(var+eps)

    hipMemsetAsync(d_ws, 0, (size_t)(V_N + 1024) * sizeof(float), stream);
    hipMemsetAsync(d_out, 0, (size_t)V_N * OUT_C * sizeof(float), stream);

    deg_kernel<<<(E_N + 255) / 256, 256, 0, stream>>>(dst, degi);
    invsqrt_kernel<<<(V_N + 255) / 256, 256, 0, stream>>>(degi);

    edge_gemm<<<dim3((E_N + BM - 1) / BM, 2), 256, 0, stream>>>(
        x, rel_repr, loop_rel, w, src, dst, etype, edir, degi, out);

    self_gemm<<<(V_N + BM - 1) / BM, 256, 0, stream>>>(
        x, loop_rel, w + 2 * IN_C * OUT_C, bias, out);

    bn_stats<<<(V_N + 255) / 256, 256, 0, stream>>>(out, sums);
    bn_finalize<<<1, 256, 0, stream>>>(sums, ms);
    bn_norm<<<2048, 256, 0, stream>>>(out, ms);

    rel_out_kernel<<<NREL2 + 1, 64, 0, stream>>>(rel_repr, loop_rel, w_rel, out);
}

// Round 2
// 424.699 us; speedup vs baseline: 12.0236x; 12.0236x over previous
//
#include <hip/hip_runtime.h>

#define V_N   100000
#define E_N   300000
#define IN_C  256
#define OUT_C 256
#define NREL2 474
#define BN_EPS 1e-5f
#define V_PAD 100032          // V rounded up to 64
#define NB_SCAN 98            // ceil(V_N/1024)

typedef __attribute__((ext_vector_type(8))) short short8;
typedef __attribute__((ext_vector_type(4))) float f32x4;

__device__ __forceinline__ unsigned short f2bf(float f) {
    unsigned int u = __builtin_bit_cast(unsigned int, f);
    u += 0x7FFFu + ((u >> 16) & 1u);          // round-to-nearest-even
    return (unsigned short)(u >> 16);
}

// ============================ NEW PATH ============================

__global__ void count_kernel(const int* __restrict__ dst, int* __restrict__ cnt) {
    int e = blockIdx.x * 256 + threadIdx.x;
    if (e < E_N) atomicAdd(&cnt[dst[e]], 1);
}

__global__ void invsqrt_cnt_kernel(const int* __restrict__ cnt, float* __restrict__ degi) {
    int v = blockIdx.x * 256 + threadIdx.x;
    if (v < V_N) {
        int c = cnt[v];
        degi[v] = c > 0 ? rsqrtf((float)c) : 0.f;
    }
}

__global__ void scan1(const int* __restrict__ cnt, int* __restrict__ bsum) {
    __shared__ int red[1024];
    int t = threadIdx.x;
    int v = blockIdx.x * 1024 + t;
    red[t] = (v < V_N) ? cnt[v] : 0;
    __syncthreads();
    for (int s = 512; s > 0; s >>= 1) {
        if (t < s) red[t] += red[t + s];
        __syncthreads();
    }
    if (t == 0) bsum[blockIdx.x] = red[0];
}

__global__ void scan2(int* bsum) {
    if (threadIdx.x == 0) {
        int run = 0;
        for (int i = 0; i < NB_SCAN; i++) { int tv = bsum[i]; bsum[i] = run; run += tv; }
    }
}

__global__ void scan3(const int* __restrict__ cnt, const int* __restrict__ bsum,
                      int* __restrict__ offs) {
    __shared__ int sc[1024];
    int t = threadIdx.x;
    int v = blockIdx.x * 1024 + t;
    int c = (v < V_N) ? cnt[v] : 0;
    sc[t] = c;
    __syncthreads();
    for (int d = 1; d < 1024; d <<= 1) {
        int add = (t >= d) ? sc[t - d] : 0;
        __syncthreads();
        sc[t] += add;
        __syncthreads();
    }
    if (v < V_N) offs[v] = sc[t] - c + bsum[blockIdx.x];
}

__global__ void scatter_kernel(const int* __restrict__ dst, const int* __restrict__ offs,
                               int* __restrict__ cursor, int* __restrict__ perm) {
    int e = blockIdx.x * 256 + threadIdx.x;
    if (e < E_N) {
        int d = dst[e];
        int pos = offs[d] + atomicAdd(&cursor[d], 1);
        perm[pos] = e;
    }
}

// WcT[n][k] = bf16(w_flat[k][n]),  k = dir*256 + i  (w is [3][IN][OUT] contiguous)
__global__ void convert_w(const float* __restrict__ w, unsigned short* __restrict__ WcT) {
    int k = blockIdx.x;    // 0..767
    int n = threadIdx.x;   // 0..255
    WcT[(size_t)n * 768 + k] = f2bf(w[(size_t)k * 256 + n]);
}

// One wave per dst node: pre[v][0..255]=dir0 agg, [256..511]=dir1 agg (bf16)
__global__ __launch_bounds__(256)
void aggregate(const float* __restrict__ x, const float* __restrict__ rel_repr,
               const float* __restrict__ degi,
               const int* __restrict__ src, const int* __restrict__ etype,
               const int* __restrict__ edir,
               const int* __restrict__ cnt, const int* __restrict__ offs,
               const int* __restrict__ perm, unsigned short* __restrict__ Apre) {
    int wid = (blockIdx.x * 256 + threadIdx.x) >> 6;
    int lane = threadIdx.x & 63;
    if (wid >= V_N) return;
    const int v = wid;
    const int n = cnt[v];
    const int base = offs[v];
    const float dv = degi[v];
    const int c4 = lane * 4;
    float4 a0 = make_float4(0.f, 0.f, 0.f, 0.f);
    float4 a1 = make_float4(0.f, 0.f, 0.f, 0.f);
    for (int i = 0; i < n; i++) {
        int e  = perm[base + i];
        int s  = src[e];
        int et = etype[e];
        float en = degi[s] * dv;
        float4 xv = *(const float4*)(x + (size_t)s * IN_C + c4);
        float4 rv = *(const float4*)(rel_repr + (size_t)et * IN_C + c4);
        float4 m;
        m.x = xv.x * rv.x * en; m.y = xv.y * rv.y * en;
        m.z = xv.z * rv.z * en; m.w = xv.w * rv.w * en;
        if (edir[e] == 0) { a0.x += m.x; a0.y += m.y; a0.z += m.z; a0.w += m.w; }
        else              { a1.x += m.x; a1.y += m.y; a1.z += m.z; a1.w += m.w; }
    }
    ushort4 u0, u1;
    u0.x = f2bf(a0.x); u0.y = f2bf(a0.y); u0.z = f2bf(a0.z); u0.w = f2bf(a0.w);
    u1.x = f2bf(a1.x); u1.y = f2bf(a1.y); u1.z = f2bf(a1.z); u1.w = f2bf(a1.w);
    *(ushort4*)(Apre + (size_t)v * 512 + c4)       = u0;
    *(ushort4*)(Apre + (size_t)v * 512 + 256 + c4) = u1;
}

// out[V][256] = [pre0 | pre1 | x*loop] @ [w0; w1; w2]  (K=768), /3 + bias
// 64 rows x 256 cols per block, 4 waves, mfma 16x16x32 bf16.
#define APAD 40   // ushort stride (80 B, 16B-aligned rows)
__global__ __launch_bounds__(256)
void mfma_gemm(const unsigned short* __restrict__ Apre, const float* __restrict__ x,
               const float* __restrict__ loop_rel, const unsigned short* __restrict__ WcT,
               const float* __restrict__ bias, float* __restrict__ out) {
    __shared__ unsigned short A_t[64][APAD];
    __shared__ unsigned short B_t[256][APAD];

    const int t = threadIdx.x;
    const int wv = t >> 6;
    const int lane = t & 63;
    const int e0 = blockIdx.x * 64;
    const int lr = lane & 15;
    const int g8 = (lane >> 4) * 8;

    f32x4 acc[4][4];
    #pragma unroll
    for (int m = 0; m < 4; m++)
        #pragma unroll
        for (int n = 0; n < 4; n++)
            acc[m][n] = (f32x4){0.f, 0.f, 0.f, 0.f};

    const int srow = t >> 2;          // staging: 4 threads per row
    const int skk  = (t & 3) * 8;     // 8 bf16 each

    for (int ks = 0; ks < 24; ks++) {
        const int k0 = ks * 32;
        // ---- stage A tile (64 x 32 bf16) ----
        if (ks < 16) {
            uint4 va = *(const uint4*)(Apre + (size_t)(e0 + srow) * 512 + k0 + skk);
            *(uint4*)&A_t[srow][skk] = va;
        } else {
            const int k0x = k0 - 512 + skk;
            const int gr = min(e0 + srow, V_N - 1);
            float4 xa = *(const float4*)(x + (size_t)gr * 256 + k0x);
            float4 xb = *(const float4*)(x + (size_t)gr * 256 + k0x + 4);
            float4 la = *(const float4*)(loop_rel + k0x);
            float4 lb = *(const float4*)(loop_rel + k0x + 4);
            ushort4 u0, u1;
            u0.x = f2bf(xa.x * la.x); u0.y = f2bf(xa.y * la.y);
            u0.z = f2bf(xa.z * la.z); u0.w = f2bf(xa.w * la.w);
            u1.x = f2bf(xb.x * lb.x); u1.y = f2bf(xb.y * lb.y);
            u1.z = f2bf(xb.z * lb.z); u1.w = f2bf(xb.w * lb.w);
            *(ushort4*)&A_t[srow][skk]     = u0;
            *(ushort4*)&A_t[srow][skk + 4] = u1;
        }
        // ---- stage B tile transposed: B_t[col][k] from WcT[col][k0..k0+31] ----
        {
            const unsigned short* wr = WcT + (size_t)t * 768 + k0;
            uint4 b0 = *(const uint4*)(wr);
            uint4 b1 = *(const uint4*)(wr + 8);
            uint4 b2 = *(const uint4*)(wr + 16);
            uint4 b3 = *(const uint4*)(wr + 24);
            *(uint4*)&B_t[t][0]  = b0;
            *(uint4*)&B_t[t][8]  = b1;
            *(uint4*)&B_t[t][16] = b2;
            *(uint4*)&B_t[t][24] = b3;
        }
        __syncthreads();

        short8 av[4], bv[4];
        #pragma unroll
        for (int m = 0; m < 4; m++)
            av[m] = *(const short8*)&A_t[m * 16 + lr][g8];
        #pragma unroll
        for (int n = 0; n < 4; n++)
            bv[n] = *(const short8*)&B_t[wv * 64 + n * 16 + lr][g8];
        #pragma unroll
        for (int m = 0; m < 4; m++)
            #pragma unroll
            for (int n = 0; n < 4; n++)
                acc[m][n] = __builtin_amdgcn_mfma_f32_16x16x32_bf16(av[m], bv[n], acc[m][n], 0, 0, 0);
        __syncthreads();
    }

    // epilogue: /3 + bias   (C/D layout: col=lane&15, row=(lane>>4)*4+reg)
    const int crow0 = (lane >> 4) * 4;
    const float inv3 = 1.f / 3.f;
    #pragma unroll
    for (int n = 0; n < 4; n++) {
        const int col = wv * 64 + n * 16 + lr;
        const float b = bias[col];
        #pragma unroll
        for (int m = 0; m < 4; m++) {
            #pragma unroll
            for (int j = 0; j < 4; j++) {
                int r = e0 + m * 16 + crow0 + j;
                if (r < V_N) out[(size_t)r * 256 + col] = acc[m][n][j] * inv3 + b;
            }
        }
    }
}

// ============================ FALLBACK PATH (round-1, known-good) ============================

#define BM 64
#define KT 32
#define LDA (BM + 4)

__global__ void deg_kernel(const int* __restrict__ dst, float* __restrict__ deg) {
    int e = blockIdx.x * 256 + threadIdx.x;
    if (e < E_N) atomicAdd(&deg[dst[e]], 1.0f);
}

__global__ void invsqrt_kernel(float* deg) {
    int v = blockIdx.x * 256 + threadIdx.x;
    if (v < V_N) {
        float d = deg[v];
        deg[v] = d > 0.f ? rsqrtf(d) : 0.f;
    }
}

__global__ __launch_bounds__(256)
void edge_gemm(const float* __restrict__ x, const float* __restrict__ rel_repr,
               const float* __restrict__ loop_rel, const float* __restrict__ w,
               const int* __restrict__ src, const int* __restrict__ dst,
               const int* __restrict__ etype, const int* __restrict__ edir,
               const float* __restrict__ inv, float* __restrict__ out)
{
    __shared__ float A_t[KT][LDA];
    __shared__ float w_lds[KT][OUT_C];
    const int t  = threadIdx.x;
    const int d  = blockIdx.y;
    const int e0 = blockIdx.x * BM;
    const int le = t & 63;
    const int kq = t >> 6;
    const int eg = e0 + le;
    int s_idx = 0, et = 0;
    bool active = false;
    if (eg < E_N) { active = (edir[eg] == d); s_idx = src[eg]; et = etype[eg]; }
    const float* xrow = x + (size_t)s_idx * IN_C;
    const float* rrow = (et < NREL2) ? (rel_repr + (size_t)et * IN_C) : loop_rel;
    const float* wmat = w + (size_t)d * IN_C * OUT_C;
    const int ec = t & 15;
    const int cc = t >> 4;
    float4 acc[4][4];
    #pragma unroll
    for (int i = 0; i < 4; i++)
        #pragma unroll
        for (int j = 0; j < 4; j++) acc[i][j] = make_float4(0.f, 0.f, 0.f, 0.f);
    for (int k0 = 0; k0 < IN_C; k0 += KT) {
        const int kb = kq * 8;
        if (active) {
            float4 xv0 = *(const float4*)(xrow + k0 + kb);
            float4 xv1 = *(const float4*)(xrow + k0 + kb + 4);
            float4 rv0 = *(const float4*)(rrow + k0 + kb);
            float4 rv1 = *(const float4*)(rrow + k0 + kb + 4);
            A_t[kb + 0][le] = xv0.x * rv0.x; A_t[kb + 1][le] = xv0.y * rv0.y;
            A_t[kb + 2][le] = xv0.z * rv0.z; A_t[kb + 3][le] = xv0.w * rv0.w;
            A_t[kb + 4][le] = xv1.x * rv1.x; A_t[kb + 5][le] = xv1.y * rv1.y;
            A_t[kb + 6][le] = xv1.z * rv1.z; A_t[kb + 7][le] = xv1.w * rv1.w;
        } else {
            #pragma unroll
            for (int i = 0; i < 8; i++) A_t[kb + i][le] = 0.f;
        }
        #pragma unroll
        for (int i = 0; i < 8; i++) {
            int idx = i * 256 + t;
            int row = idx >> 6;
            int c4  = (idx & 63) << 2;
            *(float4*)&w_lds[row][c4] = *(const float4*)(wmat + (size_t)(k0 + row) * OUT_C + c4);
        }
        __syncthreads();
        #pragma unroll
        for (int k = 0; k < KT; k++) {
            float4 a = *(const float4*)&A_t[k][ec << 2];
            float4 wv0 = *(const float4*)&w_lds[k][cc * 16 + 0];
            float4 wv1 = *(const float4*)&w_lds[k][cc * 16 + 4];
            float4 wv2 = *(const float4*)&w_lds[k][cc * 16 + 8];
            float4 wv3 = *(const float4*)&w_lds[k][cc * 16 + 12];
            float avv[4] = {a.x, a.y, a.z, a.w};
            #pragma unroll
            for (int i = 0; i < 4; i++) {
                acc[i][0].x += avv[i] * wv0.x; acc[i][0].y += avv[i] * wv0.y;
                acc[i][0].z += avv[i] * wv0.z; acc[i][0].w += avv[i] * wv0.w;
                acc[i][1].x += avv[i] * wv1.x; acc[i][1].y += avv[i] * wv1.y;
                acc[i][1].z += avv[i] * wv1.z; acc[i][1].w += avv[i] * wv1.w;
                acc[i][2].x += avv[i] * wv2.x; acc[i][2].y += avv[i] * wv2.y;
                acc[i][2].z += avv[i] * wv2.z; acc[i][2].w += avv[i] * wv2.w;
                acc[i][3].x += avv[i] * wv3.x; acc[i][3].y += avv[i] * wv3.y;
                acc[i][3].w += avv[i] * wv3.w; acc[i][3].z += avv[i] * wv3.z;
            }
        }
        __syncthreads();
    }
    #pragma unroll
    for (int i = 0; i < 4; i++) {
        int ee = e0 + ec * 4 + i;
        if (ee >= E_N) continue;
        if (edir[ee] != d) continue;
        float en = inv[src[ee]] * inv[dst[ee]];
        float* base = out + (size_t)dst[ee] * OUT_C + cc * 16;
        #pragma unroll
        for (int j = 0; j < 4; j++) {
            atomicAdd(base + j * 4 + 0, acc[i][j].x * en);
            atomicAdd(base + j * 4 + 1, acc[i][j].y * en);
            atomicAdd(base + j * 4 + 2, acc[i][j].z * en);
            atomicAdd(base + j * 4 + 3, acc[i][j].w * en);
        }
    }
}

__global__ __launch_bounds__(256)
void self_gemm(const float* __restrict__ x, const float* __restrict__ loop_rel,
               const float* __restrict__ w2, const float* __restrict__ bias,
               float* __restrict__ out)
{
    __shared__ float A_t[KT][LDA];
    __shared__ float w_lds[KT][OUT_C];
    const int t  = threadIdx.x;
    const int v0 = blockIdx.x * BM;
    const int lv = t & 63;
    const int kq = t >> 6;
    const int vg = v0 + lv;
    const float* xrow = x + (size_t)(vg < V_N ? vg : 0) * IN_C;
    const bool vok = (vg < V_N);
    const int ec = t & 15;
    const int cc = t >> 4;
    float4 acc[4][4];
    #pragma unroll
    for (int i = 0; i < 4; i++)
        #pragma unroll
        for (int j = 0; j < 4; j++) acc[i][j] = make_float4(0.f, 0.f, 0.f, 0.f);
    for (int k0 = 0; k0 < IN_C; k0 += KT) {
        const int kb = kq * 8;
        if (vok) {
            float4 xv0 = *(const float4*)(xrow + k0 + kb);
            float4 xv1 = *(const float4*)(xrow + k0 + kb + 4);
            float4 rv0 = *(const float4*)(loop_rel + k0 + kb);
            float4 rv1 = *(const float4*)(loop_rel + k0 + kb + 4);
            A_t[kb + 0][lv] = xv0.x * rv0.x; A_t[kb + 1][lv] = xv0.y * rv0.y;
            A_t[kb + 2][lv] = xv0.z * rv0.z; A_t[kb + 3][lv] = xv0.w * rv0.w;
            A_t[kb + 4][lv] = xv1.x * rv1.x; A_t[kb + 5][lv] = xv1.y * rv1.y;
            A_t[kb + 6][lv] = xv1.z * rv1.z; A_t[kb + 7][lv] = xv1.w * rv1.w;
        } else {
            #pragma unroll
            for (int i = 0; i < 8; i++) A_t[kb + i][lv] = 0.f;
        }
        #pragma unroll
        for (int i = 0; i < 8; i++) {
            int idx = i * 256 + t;
            int row = idx >> 6;
            int c4  = (idx & 63) << 2;
            *(float4*)&w_lds[row][c4] = *(const float4*)(w2 + (size_t)(k0 + row) * OUT_C + c4);
        }
        __syncthreads();
        #pragma unroll
        for (int k = 0; k < KT; k++) {
            float4 a = *(const float4*)&A_t[k][ec << 2];
            float4 wv0 = *(const float4*)&w_lds[k][cc * 16 + 0];
            float4 wv1 = *(const float4*)&w_lds[k][cc * 16 + 4];
            float4 wv2 = *(const float4*)&w_lds[k][cc * 16 + 8];
            float4 wv3 = *(const float4*)&w_lds[k][cc * 16 + 12];
            float avv[4] = {a.x, a.y, a.z, a.w};
            #pragma unroll
            for (int i = 0; i < 4; i++) {
                acc[i][0].x += avv[i] * wv0.x; acc[i][0].y += avv[i] * wv0.y;
                acc[i][0].z += avv[i] * wv0.z; acc[i][0].w += avv[i] * wv0.w;
                acc[i][1].x += avv[i] * wv1.x; acc[i][1].y += avv[i] * wv1.y;
                acc[i][1].z += avv[i] * wv1.z; acc[i][1].w += avv[i] * wv1.w;
                acc[i][2].x += avv[i] * wv2.x; acc[i][2].y += avv[i] * wv2.y;
                acc[i][2].z += avv[i] * wv2.z; acc[i][2].w += avv[i] * wv2.w;
                acc[i][3].x += avv[i] * wv3.x; acc[i][3].y += avv[i] * wv3.y;
                acc[i][3].z += avv[i] * wv3.z; acc[i][3].w += avv[i] * wv3.w;
            }
        }
        __syncthreads();
    }
    const float inv3 = 1.0f / 3.0f;
    #pragma unroll
    for (int i = 0; i < 4; i++) {
        int vv = v0 + ec * 4 + i;
        if (vv >= V_N) continue;
        float* base = out + (size_t)vv * OUT_C + cc * 16;
        #pragma unroll
        for (int j = 0; j < 4; j++) {
            float4 cur = *(const float4*)(base + j * 4);
            float4 b4  = *(const float4*)(bias + cc * 16 + j * 4);
            float4 r;
            r.x = (cur.x + acc[i][j].x) * inv3 + b4.x;
            r.y = (cur.y + acc[i][j].y) * inv3 + b4.y;
            r.z = (cur.z + acc[i][j].z) * inv3 + b4.z;
            r.w = (cur.w + acc[i][j].w) * inv3 + b4.w;
            *(float4*)(base + j * 4) = r;
        }
    }
}

// ============================ shared tail kernels ============================

__global__ void bn_stats(const float* __restrict__ out, float* __restrict__ sums) {
    int t  = threadIdx.x;
    int r0 = blockIdx.x * 256;
    float s = 0.f, s2 = 0.f;
    for (int i = 0; i < 256; i++) {
        int r = r0 + i;
        if (r < V_N) {
            float v = out[(size_t)r * OUT_C + t];
            s += v; s2 += v * v;
        }
    }
    atomicAdd(&sums[t], s);
    atomicAdd(&sums[256 + t], s2);
}

__global__ void bn_finalize(const float* __restrict__ sums, float* __restrict__ ms) {
    int t = threadIdx.x;
    float m   = sums[t] / (float)V_N;
    float var = sums[256 + t] / (float)V_N - m * m;
    ms[t]       = m;
    ms[256 + t] = rsqrtf(var + BN_EPS);
}

__global__ void bn_norm(float* __restrict__ out, const float* __restrict__ ms) {
    const size_t total4 = (size_t)V_N * OUT_C / 4;
    size_t stride = (size_t)gridDim.x * blockDim.x;
    for (size_t idx = (size_t)blockIdx.x * blockDim.x + threadIdx.x; idx < total4; idx += stride) {
        int c4 = (int)(idx & 63) << 2;
        float4 h = ((float4*)out)[idx];
        h.x = (h.x - ms[c4 + 0]) * ms[256 + c4 + 0];
        h.y = (h.y - ms[c4 + 1]) * ms[256 + c4 + 1];
        h.z = (h.z - ms[c4 + 2]) * ms[256 + c4 + 2];
        h.w = (h.w - ms[c4 + 3]) * ms[256 + c4 + 3];
        ((float4*)out)[idx] = h;
    }
}

__global__ void rel_out_kernel(const float* __restrict__ rel_repr,
                               const float* __restrict__ loop_rel,
                               const float* __restrict__ w_rel,
                               float* __restrict__ out)
{
    int r = blockIdx.x;
    const float* row = (r < NREL2) ? (rel_repr + (size_t)r * IN_C) : loop_rel;
    int l = threadIdx.x;
    float s = 0.f;
    #pragma unroll
    for (int q = 0; q < 4; q++) {
        int k = l + q * 64;
        s += row[k] * w_rel[(size_t)k * OUT_C + (OUT_C - 1)];
    }
    #pragma unroll
    for (int m = 32; m >= 1; m >>= 1) s += __shfl_xor(s, m);
    if (l == 0) out[(size_t)V_N * OUT_C + r] = s;
}

// ============================ launch ============================

extern "C" void kernel_launch(void* const* d_in, const int* in_sizes, int n_in,
                              void* d_out, int out_size, void* d_ws, size_t ws_size,
                              hipStream_t stream) {
    const float* x        = (const float*)d_in[0];
    const float* rel_repr = (const float*)d_in[1];
    const float* w        = (const float*)d_in[2];
    const float* w_rel    = (const float*)d_in[3];
    const float* loop_rel = (const float*)d_in[4];
    const float* bias     = (const float*)d_in[5];
    const int*   src      = (const int*)d_in[6];
    const int*   dst      = (const int*)d_in[7];
    const int*   etype    = (const int*)d_in[8];
    const int*   edir     = (const int*)d_in[9];
    float* out = (float*)d_out;

    // ---- new-path workspace layout ----
    char* wsb = (char*)d_ws;
    int*   cnt    = (int*)wsb;                 // V
    int*   cursor = cnt + V_N;                 // V
    float* sums   = (float*)(cursor + V_N);    // 512
    float* ms     = sums + 512;                // 512
    int*   offs   = (int*)(ms + 512);          // V
    int*   perm   = offs + V_N;                // E
    int*   bsum   = perm + E_N;                // 128
    float* degi   = (float*)(bsum + 128);      // V
    size_t head = (size_t)((char*)(degi + V_N) - wsb);
    head = (head + 255) & ~(size_t)255;
    unsigned short* Apre = (unsigned short*)(wsb + head);              // V_PAD*512 bf16
    unsigned short* WcT  = Apre + (size_t)V_PAD * 512;                 // 256*768 bf16
    size_t need = head + ((size_t)V_PAD * 512 + (size_t)768 * 256) * 2;

    if (ws_size >= need) {
        // zero cnt+cursor (+sums)
        hipMemsetAsync(wsb, 0, (size_t)(2 * V_N) * 4 + 2048, stream);

        count_kernel<<<(E_N + 255) / 256, 256, 0, stream>>>(dst, cnt);
        invsqrt_cnt_kernel<<<(V_N + 255) / 256, 256, 0, stream>>>(cnt, degi);
        scan1<<<NB_SCAN, 1024, 0, stream>>>(cnt, bsum);
        scan2<<<1, 64, 0, stream>>>(bsum);
        scan3<<<NB_SCAN, 1024, 0, stream>>>(cnt, bsum, offs);
        scatter_kernel<<<(E_N + 255) / 256, 256, 0, stream>>>(dst, offs, cursor, perm);
        convert_w<<<768, 256, 0, stream>>>(w, WcT);
        aggregate<<<(V_N + 3) / 4, 256, 0, stream>>>(x, rel_repr, degi, src, etype, edir,
                                                     cnt, offs, perm, Apre);
        mfma_gemm<<<V_PAD / 64, 256, 0, stream>>>(Apre, x, loop_rel, WcT, bias, out);

        bn_stats<<<(V_N + 255) / 256, 256, 0, stream>>>(out, sums);
        bn_finalize<<<1, 256, 0, stream>>>(sums, ms);
        bn_norm<<<2048, 256, 0, stream>>>(out, ms);
        rel_out_kernel<<<NREL2 + 1, 64, 0, stream>>>(rel_repr, loop_rel, w_rel, out);
    } else {
        // ---- fallback: round-1 known-good path ----
        float* fdegi = (float*)d_ws;
        float* fsums = fdegi + V_N;
        float* fms   = fsums + 512;
        hipMemsetAsync(d_ws, 0, (size_t)(V_N + 1024) * sizeof(float), stream);
        hipMemsetAsync(d_out, 0, (size_t)V_N * OUT_C * sizeof(float), stream);
        deg_kernel<<<(E_N + 255) / 256, 256, 0, stream>>>(dst, fdegi);
        invsqrt_kernel<<<(V_N + 255) / 256, 256, 0, stream>>>(fdegi);
        edge_gemm<<<dim3((E_N + BM - 1) / BM, 2), 256, 0, stream>>>(
            x, rel_repr, loop_rel, w, src, dst, etype, edir, fdegi, out);
        self_gemm<<<(V_N + BM - 1) / BM, 256, 0, stream>>>(
            x, loop_rel, w + 2 * IN_C * OUT_C, bias, out);
        bn_stats<<<(V_N + 255) / 256, 256, 0, stream>>>(out, fsums);
        bn_finalize<<<1, 256, 0, stream>>>(fsums, fms);
        bn_norm<<<2048, 256, 0, stream>>>(out, fms);
        rel_out_kernel<<<NREL2 + 1, 64, 0, stream>>>(rel_repr, loop_rel, w_rel, out);
    }
}

// Round 3
// 351.342 us; speedup vs baseline: 14.5340x; 1.2088x over previous
//
#include <hip/hip_runtime.h>

#define V_N   100000
#define E_N   300000
#define IN_C  256
#define OUT_C 256
#define NREL2 474
#define BN_EPS 1e-5f
#define NB_SCAN 98            // ceil(V_N/1024)
#define MTILES 782            // ceil(V_N/128)

typedef __attribute__((ext_vector_type(8))) short short8;
typedef __attribute__((ext_vector_type(4))) float f32x4;

__device__ __forceinline__ unsigned short f2bf(float f) {
    unsigned int u = __builtin_bit_cast(unsigned int, f);
    u += 0x7FFFu + ((u >> 16) & 1u);          // RNE
    return (unsigned short)(u >> 16);
}
__device__ __forceinline__ unsigned int pk2bf(float lo, float hi) {
    return (unsigned int)f2bf(lo) | ((unsigned int)f2bf(hi) << 16);
}

typedef const __attribute__((address_space(1))) unsigned int* gas1_t;
typedef __attribute__((address_space(3))) unsigned int* las3_t;
__device__ __forceinline__ void gload16(const void* g, void* l) {
    __builtin_amdgcn_global_load_lds((gas1_t)g, (las3_t)l, 16, 0, 0);
}

// ---------------- CSR build ----------------

__global__ void count_kernel(const int* __restrict__ dst, int* __restrict__ cnt) {
    int e = blockIdx.x * 256 + threadIdx.x;
    if (e < E_N) atomicAdd(&cnt[dst[e]], 1);
}

__global__ void invsqrt_cnt_kernel(const int* __restrict__ cnt, float* __restrict__ degi) {
    int v = blockIdx.x * 256 + threadIdx.x;
    if (v < V_N) {
        int c = cnt[v];
        degi[v] = c > 0 ? rsqrtf((float)c) : 0.f;
    }
}

__global__ void scan1(const int* __restrict__ cnt, int* __restrict__ bsum) {
    __shared__ int red[1024];
    int t = threadIdx.x;
    int v = blockIdx.x * 1024 + t;
    red[t] = (v < V_N) ? cnt[v] : 0;
    __syncthreads();
    for (int s = 512; s > 0; s >>= 1) {
        if (t < s) red[t] += red[t + s];
        __syncthreads();
    }
    if (t == 0) bsum[blockIdx.x] = red[0];
}

__global__ void scan2(int* bsum) {
    if (threadIdx.x == 0) {
        int run = 0;
        for (int i = 0; i < NB_SCAN; i++) { int tv = bsum[i]; bsum[i] = run; run += tv; }
    }
}

__global__ void scan3(const int* __restrict__ cnt, const int* __restrict__ bsum,
                      int* __restrict__ offs) {
    __shared__ int sc[1024];
    int t = threadIdx.x;
    int v = blockIdx.x * 1024 + t;
    int c = (v < V_N) ? cnt[v] : 0;
    sc[t] = c;
    __syncthreads();
    for (int d = 1; d < 1024; d <<= 1) {
        int add = (t >= d) ? sc[t - d] : 0;
        __syncthreads();
        sc[t] += add;
        __syncthreads();
    }
    if (v < V_N) offs[v] = sc[t] - c + bsum[blockIdx.x];
}

// pack src|etype|dir into one word per CSR slot (shortens aggregate's dep chain)
__global__ void scatter_kernel(const int* __restrict__ dst, const int* __restrict__ src,
                               const int* __restrict__ etype, const int* __restrict__ edir,
                               const int* __restrict__ offs, int* __restrict__ cursor,
                               int* __restrict__ epack) {
    int e = blockIdx.x * 256 + threadIdx.x;
    if (e < E_N) {
        int d = dst[e];
        int pos = offs[d] + atomicAdd(&cursor[d], 1);
        epack[pos] = src[e] | (etype[e] << 17) | (edir[e] << 26);
    }
}

// WcT[n][k] = bf16(w_flat[k][n]), k = dir*256 + i  (w is [3][IN][OUT] contiguous)
__global__ void convert_w(const float* __restrict__ w, unsigned short* __restrict__ WcT) {
    int k = blockIdx.x;    // 0..767
    int n = threadIdx.x;   // 0..255
    WcT[(size_t)n * 768 + k] = f2bf(w[(size_t)k * 256 + n]);
}

// ---------------- aggregate: one wave per dst node ----------------
// Apre[v][0..255]=dir0 agg, [256..511]=dir1 agg (bf16)
__global__ __launch_bounds__(256)
void aggregate(const float* __restrict__ x, const float* __restrict__ rel_repr,
               const float* __restrict__ degi,
               const int* __restrict__ cnt, const int* __restrict__ offs,
               const int* __restrict__ epack, unsigned short* __restrict__ Apre) {
    int wid = (blockIdx.x * 256 + threadIdx.x) >> 6;
    int lane = threadIdx.x & 63;
    if (wid >= V_N) return;
    const int v = wid;
    const int n = cnt[v];
    const int base = offs[v];
    const float dv = degi[v];
    const int c4 = lane * 4;
    float4 a0 = make_float4(0.f, 0.f, 0.f, 0.f);
    float4 a1 = make_float4(0.f, 0.f, 0.f, 0.f);
    for (int i = 0; i < n; i++) {
        int p  = epack[base + i];
        int s  = p & 0x1FFFF;
        int et = (p >> 17) & 0x1FF;
        float en = degi[s] * dv;
        float4 xv = *(const float4*)(x + (size_t)s * IN_C + c4);
        float4 rv = *(const float4*)(rel_repr + (size_t)et * IN_C + c4);
        float4 m;
        m.x = xv.x * rv.x * en; m.y = xv.y * rv.y * en;
        m.z = xv.z * rv.z * en; m.w = xv.w * rv.w * en;
        if (p & (1 << 26)) { a1.x += m.x; a1.y += m.y; a1.z += m.z; a1.w += m.w; }
        else               { a0.x += m.x; a0.y += m.y; a0.z += m.z; a0.w += m.w; }
    }
    ushort4 u0, u1;
    u0.x = f2bf(a0.x); u0.y = f2bf(a0.y); u0.z = f2bf(a0.z); u0.w = f2bf(a0.w);
    u1.x = f2bf(a1.x); u1.y = f2bf(a1.y); u1.z = f2bf(a1.z); u1.w = f2bf(a1.w);
    *(ushort4*)(Apre + (size_t)v * 512 + c4)       = u0;
    *(ushort4*)(Apre + (size_t)v * 512 + 256 + c4) = u1;
}

// ---------------- fused GEMM: out = [Apre | x*loop] @ WcT^T, /3 + bias, BN partials ----------------
// 128 rows x 256 cols per block, 512 threads = 8 waves (2x4), each wave 64x64.
// K = 768 in 12 steps of BK=64. LDS chunks (16B) XOR-swizzled via pre-swizzled
// global source (global_load_lds writes linearly; read applies same swizzle).
__global__ __launch_bounds__(512)
void mfma_gemm(const unsigned short* __restrict__ Apre, const float* __restrict__ x,
               const float* __restrict__ loop_rel, const unsigned short* __restrict__ WcT,
               const float* __restrict__ bias, float* __restrict__ out,
               float* __restrict__ partial) {
    __shared__ unsigned short A_sh[8192];    // 128 rows x 64 k  (1024 chunks)
    __shared__ unsigned short B_sh[16384];   // 256 cols x 64 k  (2048 chunks)

    const int t    = threadIdx.x;
    const int m0   = blockIdx.x * 128;
    const int wid  = t >> 6;
    const int lane = t & 63;
    const int wm   = wid >> 2;          // 0..1
    const int wn   = wid & 3;           // 0..3
    const int lr   = lane & 15;
    const int qk   = lane >> 4;         // 0..3
    const int sxr  = lr & 7;
    const int wbase = t & 0x1C0;        // wave id * 64

    f32x4 acc[4][4];
    #pragma unroll
    for (int m = 0; m < 4; m++)
        #pragma unroll
        for (int n = 0; n < 4; n++)
            acc[m][n] = (f32x4){0.f, 0.f, 0.f, 0.f};

    for (int ks = 0; ks < 12; ++ks) {
        const int k0 = ks * 64;
        if (ks) __syncthreads();        // prev compute done before overwrite
        if (ks < 8) {
            // A tile via global_load_lds, pre-swizzled source
            #pragma unroll
            for (int j = 0; j < 2; ++j) {
                int g = j * 512 + t;
                int row = g >> 3, c = g & 7;
                int rg = m0 + row; if (rg >= V_N) rg = V_N - 1;
                const unsigned short* src = Apre + (size_t)rg * 512 + k0 + ((c ^ (row & 7)) << 3);
                gload16(src, &A_sh[(size_t)(j * 512 + wbase) * 8]);
            }
        } else {
            // self-loop part: reg-stage x*loop -> bf16 -> swizzled ds_write
            const int kx = k0 - 512;
            const int row = t >> 2;
            int rg = m0 + row; if (rg >= V_N) rg = V_N - 1;
            const int cq = (t & 3) * 2;
            const float* xs = x + (size_t)rg * 256 + kx + (t & 3) * 16;
            const float* ls = loop_rel + kx + (t & 3) * 16;
            float4 x0 = *(const float4*)(xs);
            float4 x1 = *(const float4*)(xs + 4);
            float4 x2 = *(const float4*)(xs + 8);
            float4 x3 = *(const float4*)(xs + 12);
            float4 l0 = *(const float4*)(ls);
            float4 l1 = *(const float4*)(ls + 4);
            float4 l2 = *(const float4*)(ls + 8);
            float4 l3 = *(const float4*)(ls + 12);
            uint4 u0, u1;
            u0.x = pk2bf(x0.x * l0.x, x0.y * l0.y);
            u0.y = pk2bf(x0.z * l0.z, x0.w * l0.w);
            u0.z = pk2bf(x1.x * l1.x, x1.y * l1.y);
            u0.w = pk2bf(x1.z * l1.z, x1.w * l1.w);
            u1.x = pk2bf(x2.x * l2.x, x2.y * l2.y);
            u1.y = pk2bf(x2.z * l2.z, x2.w * l2.w);
            u1.z = pk2bf(x3.x * l3.x, x3.y * l3.y);
            u1.w = pk2bf(x3.z * l3.z, x3.w * l3.w);
            *(uint4*)&A_sh[(size_t)(row * 8 + (cq ^ (row & 7))) * 8]       = u0;
            *(uint4*)&A_sh[(size_t)(row * 8 + ((cq + 1) ^ (row & 7))) * 8] = u1;
        }
        // B tile via global_load_lds (all steps)
        #pragma unroll
        for (int j = 0; j < 4; ++j) {
            int g = j * 512 + t;
            int n = g >> 3, c = g & 7;
            const unsigned short* src = WcT + (size_t)n * 768 + k0 + ((c ^ (n & 7)) << 3);
            gload16(src, &B_sh[(size_t)(j * 512 + wbase) * 8]);
        }
        __syncthreads();                // drains vmcnt + lgkmcnt (compiler)

        #pragma unroll
        for (int h = 0; h < 2; ++h) {
            short8 av[4], bv[4];
            #pragma unroll
            for (int m = 0; m < 4; m++) {
                int row = wm * 64 + m * 16 + lr;
                av[m] = *(const short8*)&A_sh[(size_t)(row * 8 + ((h * 4 + qk) ^ sxr)) * 8];
            }
            #pragma unroll
            for (int n = 0; n < 4; n++) {
                int col = wn * 64 + n * 16 + lr;
                bv[n] = *(const short8*)&B_sh[(size_t)(col * 8 + ((h * 4 + qk) ^ sxr)) * 8];
            }
            #pragma unroll
            for (int m = 0; m < 4; m++)
                #pragma unroll
                for (int n = 0; n < 4; n++)
                    acc[m][n] = __builtin_amdgcn_mfma_f32_16x16x32_bf16(av[m], bv[n], acc[m][n], 0, 0, 0);
        }
    }

    // ---- epilogue: /3 + bias, write out, per-block BN column partials ----
    __syncthreads();
    float* bs = (float*)A_sh;           // 512 floats: [s(256) | s2(256)]
    bs[t & 511] = 0.f;                  // t<512, each zeroes one
    __syncthreads();

    const float inv3 = 1.f / 3.f;
    const int crow0 = qk * 4;
    float s[4]  = {0.f, 0.f, 0.f, 0.f};
    float s2[4] = {0.f, 0.f, 0.f, 0.f};
    #pragma unroll
    for (int n = 0; n < 4; n++) {
        const int col = wn * 64 + n * 16 + lr;
        const float b = bias[col];
        #pragma unroll
        for (int m = 0; m < 4; m++) {
            #pragma unroll
            for (int j = 0; j < 4; j++) {
                int r = m0 + wm * 64 + m * 16 + crow0 + j;
                if (r < V_N) {
                    float h = acc[m][n][j] * inv3 + b;
                    out[(size_t)r * 256 + col] = h;
                    s[n] += h; s2[n] += h * h;
                }
            }
        }
    }
    #pragma unroll
    for (int n = 0; n < 4; n++) {
        s[n]  += __shfl_xor(s[n], 16);  s[n]  += __shfl_xor(s[n], 32);
        s2[n] += __shfl_xor(s2[n], 16); s2[n] += __shfl_xor(s2[n], 32);
    }
    if (lane < 16) {
        #pragma unroll
        for (int n = 0; n < 4; n++) {
            const int col = wn * 64 + n * 16 + lr;
            atomicAdd(&bs[col], s[n]);
            atomicAdd(&bs[256 + col], s2[n]);
        }
    }
    __syncthreads();
    partial[(size_t)blockIdx.x * 512 + t] = bs[t];
}

// ---------------- BN reduce + finalize + normalize ----------------

__global__ void bn_reduce_part(const float* __restrict__ partial, float* __restrict__ sums) {
    int t = threadIdx.x;                       // 512
    int b0 = blockIdx.x * 196;
    int b1 = b0 + 196; if (b1 > MTILES) b1 = MTILES;
    float S = 0.f;
    for (int b = b0; b < b1; b++) S += partial[(size_t)b * 512 + t];
    atomicAdd(&sums[t], S);
}

__global__ void bn_finalize(const float* __restrict__ sums, float* __restrict__ ms) {
    int c = threadIdx.x;                       // 256
    float mean = sums[c] / (float)V_N;
    float var  = sums[256 + c] / (float)V_N - mean * mean;
    ms[c]       = mean;
    ms[256 + c] = rsqrtf(var + BN_EPS);
}

__global__ void bn_norm(float* __restrict__ out, const float* __restrict__ ms) {
    const size_t total4 = (size_t)V_N * OUT_C / 4;
    size_t stride = (size_t)gridDim.x * blockDim.x;
    for (size_t idx = (size_t)blockIdx.x * blockDim.x + threadIdx.x; idx < total4; idx += stride) {
        int c4 = (int)(idx & 63) << 2;
        float4 h = ((float4*)out)[idx];
        h.x = (h.x - ms[c4 + 0]) * ms[256 + c4 + 0];
        h.y = (h.y - ms[c4 + 1]) * ms[256 + c4 + 1];
        h.z = (h.z - ms[c4 + 2]) * ms[256 + c4 + 2];
        h.w = (h.w - ms[c4 + 3]) * ms[256 + c4 + 3];
        ((float4*)out)[idx] = h;
    }
}

__global__ void rel_out_kernel(const float* __restrict__ rel_repr,
                               const float* __restrict__ loop_rel,
                               const float* __restrict__ w_rel,
                               float* __restrict__ out)
{
    int r = blockIdx.x;
    const float* row = (r < NREL2) ? (rel_repr + (size_t)r * IN_C) : loop_rel;
    int l = threadIdx.x;
    float s = 0.f;
    #pragma unroll
    for (int q = 0; q < 4; q++) {
        int k = l + q * 64;
        s += row[k] * w_rel[(size_t)k * OUT_C + (OUT_C - 1)];
    }
    #pragma unroll
    for (int m = 32; m >= 1; m >>= 1) s += __shfl_xor(s, m);
    if (l == 0) out[(size_t)V_N * OUT_C + r] = s;
}

// ---------------- launch ----------------

extern "C" void kernel_launch(void* const* d_in, const int* in_sizes, int n_in,
                              void* d_out, int out_size, void* d_ws, size_t ws_size,
                              hipStream_t stream) {
    const float* x        = (const float*)d_in[0];
    const float* rel_repr = (const float*)d_in[1];
    const float* w        = (const float*)d_in[2];
    const float* w_rel    = (const float*)d_in[3];
    const float* loop_rel = (const float*)d_in[4];
    const float* bias     = (const float*)d_in[5];
    const int*   src      = (const int*)d_in[6];
    const int*   dst      = (const int*)d_in[7];
    const int*   etype    = (const int*)d_in[8];
    const int*   edir     = (const int*)d_in[9];
    float* out = (float*)d_out;

    // workspace layout (total 105.60 MB, <= round-2-proven 105.63 MB)
    char* wsb = (char*)d_ws;
    int*   cnt     = (int*)(wsb + 0);              // 400,000
    int*   cursor  = (int*)(wsb + 400000);         // 400,000
    int*   offs    = (int*)(wsb + 800000);         // 400,000
    float* degi    = (float*)(wsb + 1200000);      // 400,000
    int*   bsum    = (int*)(wsb + 1600000);        // 392
    float* partial = (float*)(wsb + 0);            // alias region0 (1,601,536 <= 1,601,792)
    int*   epack   = (int*)(wsb + 1601792);        // 1,200,000
    float* ms      = (float*)(wsb + 2801792);      // 2048 (ms) + 2048 (sums)
    float* sums    = ms + 512;
    unsigned short* WcT  = (unsigned short*)(wsb + 2805888);   // 393,216
    unsigned short* Apre = (unsigned short*)(wsb + 3199104);   // 102,400,000

    hipMemsetAsync(wsb, 0, 800000, stream);                    // cnt + cursor
    hipMemsetAsync(sums, 0, 2048, stream);

    count_kernel<<<(E_N + 255) / 256, 256, 0, stream>>>(dst, cnt);
    invsqrt_cnt_kernel<<<(V_N + 255) / 256, 256, 0, stream>>>(cnt, degi);
    scan1<<<NB_SCAN, 1024, 0, stream>>>(cnt, bsum);
    scan2<<<1, 64, 0, stream>>>(bsum);
    scan3<<<NB_SCAN, 1024, 0, stream>>>(cnt, bsum, offs);
    scatter_kernel<<<(E_N + 255) / 256, 256, 0, stream>>>(dst, src, etype, edir,
                                                          offs, cursor, epack);
    convert_w<<<768, 256, 0, stream>>>(w, WcT);
    aggregate<<<(V_N + 3) / 4, 256, 0, stream>>>(x, rel_repr, degi, cnt, offs, epack, Apre);
    mfma_gemm<<<MTILES, 512, 0, stream>>>(Apre, x, loop_rel, WcT, bias, out, partial);
    bn_reduce_part<<<4, 512, 0, stream>>>(partial, sums);
    bn_finalize<<<1, 256, 0, stream>>>(sums, ms);
    bn_norm<<<2048, 256, 0, stream>>>(out, ms);
    rel_out_kernel<<<NREL2 + 1, 64, 0, stream>>>(rel_repr, loop_rel, w_rel, out);
}